// Round 18
// baseline (138.584 us; speedup 1.0000x reference)
//
#include <hip/hip_runtime.h>

// BitPredictor: scalar LSTM (hidden=1) iterated FEATURES times; output is one
// 512-float row broadcast across the 65536-row batch (batch dim degenerate).
//
// R2:  380us = single-lane serial recurrence -> fixed-point early exit +
//      exp2/rcp gates. Kernel ~40us after.
// R7/R9: opposite store layouts both ~3.2 TB/s vs fill 6.6 -> addressing out.
// R11: long-lived waves: 40->35us (real, small). R13: nt stores: null.
// R17: fill-matched occupancy shape (256x192, dense window): null (35.7us).
//      Four store patterns span only 3.2-3.8 TB/s; fill does 6.5 in-graph.
// R18: last surviving theory = stores contend with L2 fully dirty from the
//      512MiB ws-poison + 128MiB out-poison fills right before us. nt only
//      changed replacement policy; sc0 sc1 changes SCOPE (system) -> stores
//      bypass L2's dirty lines entirely, stream to MALL/HBM. Single change.
#define FEATURES 512

typedef float v4f __attribute__((ext_vector_type(4)));

__device__ __forceinline__ float fast_sigm(float v) {
    const float L2E = 1.44269504f;
    float e = __builtin_amdgcn_exp2f(-L2E * v);
    return __builtin_amdgcn_rcpf(1.0f + e);
}
__device__ __forceinline__ float fast_tanh(float v) {
    const float L2E2 = 2.88539008f;
    float e = __builtin_amdgcn_exp2f(L2E2 * v);
    return 1.0f - 2.0f * __builtin_amdgcn_rcpf(e + 1.0f);
}

// 256 blocks x 192 threads: one block per CU, 3 waves each (R17 shape).
__global__ __launch_bounds__(192) void bitpred_kernel(
    const float* __restrict__ Wi, const float* __restrict__ Wh,
    const float* __restrict__ b, float* __restrict__ out,
    long long total4)
{
    __shared__ float hrow[FEATURES];
    __shared__ float s_hf;
    __shared__ int s_t;

    if (threadIdx.x == 0) {
        // x == h invariant (x0 = h0 = 0, x_{t+1} = h_{t+1}) => gates use Wi+Wh.
        const float w0 = Wi[0] + Wh[0], w1 = Wi[1] + Wh[1];
        const float w2 = Wi[2] + Wh[2], w3 = Wi[3] + Wh[3];
        const float b0 = b[0], b1 = b[1], b2 = b[2], b3 = b[3];
        float c = 0.f, h = 0.f;
        float pc = 0.f, ph = 0.f;
        int t = 0;
        for (; t < FEATURES; ++t) {
            // gate order from jnp.split: i, f, g, o
            float gi = fmaf(h, w0, b0);
            float gf = fmaf(h, w1, b1);
            float gg = fmaf(h, w2, b2);
            float go = fmaf(h, w3, b3);
            c = fast_sigm(gf) * c + fast_sigm(gi) * fast_tanh(gg);
            h = fast_sigm(go) * fast_tanh(c);
            hrow[t] = h;
            // Bitwise fixed point => all subsequent h identical. (b=0: t=0.)
            if (c == pc && h == ph) break;
            pc = c; ph = h;
        }
        s_hf = h;
        s_t = t;
    }
    __syncthreads();
    // Parallel remainder fill.
    {
        const float hf = s_hf;
        for (int k = s_t + 1 + (int)threadIdx.x; k < FEATURES; k += 192)
            hrow[k] = hf;
    }
    __syncthreads();

    // Dense grid-stride window (R17), but system-scope stores: sc0 sc1
    // moves the coherence point past the (poison-dirty) L2.
    const long long nthreads = 49152;  // 256 * 192
    const long long gid = (long long)blockIdx.x * 192 + threadIdx.x;
    const v4f* hrow4 = (const v4f*)hrow;
    const v4f val = hrow4[gid & 127];
    v4f* __restrict__ out4 = (v4f*)out;
#pragma unroll 4
    for (long long i = gid; i < total4; i += nthreads) {
        v4f* p = out4 + i;
        asm volatile("global_store_dwordx4 %0, %1, off sc0 sc1"
                     :
                     : "v"(p), "v"(val)
                     : "memory");
    }
}

extern "C" void kernel_launch(void* const* d_in, const int* in_sizes, int n_in,
                              void* d_out, int out_size, void* d_ws, size_t ws_size,
                              hipStream_t stream) {
    // setup_inputs order: batch_size (int scalar), Wi (4 f32), Wh (4 f32), b (4 f32)
    const float* Wi = (const float*)d_in[1];
    const float* Wh = (const float*)d_in[2];
    const float* b  = (const float*)d_in[3];
    float* out = (float*)d_out;

    long long total4 = (long long)out_size / 4;  // 8,388,608 float4s (128 MiB)
    hipLaunchKernelGGL(bitpred_kernel, dim3(256), dim3(192), 0, stream,
                       Wi, Wh, b, out, total4);
}